// Round 1
// baseline (171.984 us; speedup 1.0000x reference)
//
#include <hip/hip_runtime.h>

// Problem constants (from reference)
#define BATCH 16
#define NENT  512
#define D_IN  256
#define D_OUT 32
#define CSP   64
#define COUT  96        // 64 spatial + 32 scatter channels
#define HWDIM 256
#define HWSZ  65536     // 256*256
#define HW4   16384     // HWSZ/4

// K1: copy spatial -> out[:, :64], zero out[:, 64:96], and zero owner[] in d_ws.
// float4/int4 vectorized, grid-stride.
__global__ void copy_zero_kernel(const float4* __restrict__ sp,
                                 float4* __restrict__ out,
                                 int4* __restrict__ owner) {
    const int total_out4 = BATCH * COUT * HW4;     // 25,165,824
    const int owner4     = BATCH * HWSZ / 4;       // 262,144
    const int total      = total_out4 + owner4;
    const int stride = gridDim.x * blockDim.x;
    for (int i = blockIdx.x * blockDim.x + threadIdx.x; i < total; i += stride) {
        if (i < total_out4) {
            int b  = i / (COUT * HW4);
            int r  = i - b * (COUT * HW4);
            int c  = r / HW4;
            int hw = r - c * HW4;
            float4 v;
            if (c < CSP) {
                v = sp[(b * CSP + c) * HW4 + hw];
            } else {
                v = make_float4(0.f, 0.f, 0.f, 0.f);
            }
            out[i] = v;
        } else {
            owner[i - total_out4] = make_int4(0, 0, 0, 0);
        }
    }
}

// K2: last-write-wins resolution. owner[b, flat] = max(n+1) over entities.
__global__ void owner_kernel(const int* __restrict__ loc,
                             int* __restrict__ owner) {
    int gid = blockIdx.x * blockDim.x + threadIdx.x;   // 0 .. 8191
    if (gid >= BATCH * NENT) return;
    int h = loc[gid * 2 + 0];
    int w = loc[gid * 2 + 1];
    h = min(max(h, 0), HWDIM - 1);
    w = min(max(w, 0), HWDIM - 1);
    int b = gid >> 9;            // / NENT
    int n = gid & (NENT - 1);
    atomicMax(&owner[b * HWSZ + h * HWDIM + w], n + 1);
}

// K3: projection + scatter. One thread per (b, n, e); 32 e-lanes per entity.
// W column reads coalesce across e-lanes; emb element broadcasts within group.
__global__ void proj_scatter_kernel(const float* __restrict__ emb,
                                    const float* __restrict__ Wp,
                                    const float* __restrict__ bp,
                                    const int* __restrict__ loc,
                                    const int* __restrict__ owner,
                                    float* __restrict__ out) {
    int gid = blockIdx.x * blockDim.x + threadIdx.x;   // 0 .. 262143
    int ent = gid >> 5;          // entity index 0..8191
    int e   = gid & 31;          // output feature 0..31
    int b   = ent >> 9;
    int n   = ent & (NENT - 1);

    int h = loc[ent * 2 + 0];
    int w = loc[ent * 2 + 1];
    h = min(max(h, 0), HWDIM - 1);
    w = min(max(w, 0), HWDIM - 1);
    int flat = h * HWDIM + w;

    if (owner[b * HWSZ + flat] != n + 1) return;   // a later entity owns this slot

    float acc = bp[e];
    const float* er = emb + ent * D_IN;
    #pragma unroll 8
    for (int d = 0; d < D_IN; ++d) {
        acc += er[d] * Wp[d * D_OUT + e];
    }
    out[b * (COUT * HWSZ) + (CSP + e) * HWSZ + flat] = acc;
}

extern "C" void kernel_launch(void* const* d_in, const int* in_sizes, int n_in,
                              void* d_out, int out_size, void* d_ws, size_t ws_size,
                              hipStream_t stream) {
    const float* spatial = (const float*)d_in[0];   // [16,64,256,256]
    const float* emb     = (const float*)d_in[1];   // [16,512,256]
    const float* Wp      = (const float*)d_in[2];   // [256,32]
    const float* bp      = (const float*)d_in[3];   // [32]
    const int*   loc     = (const int*)d_in[4];     // [16,512,2]
    float* out = (float*)d_out;                     // [16,96,256,256]
    int* owner = (int*)d_ws;                        // 16*65536 ints = 4 MB

    // K1: copy + zero (memory-bound bulk)
    copy_zero_kernel<<<2048, 256, 0, stream>>>((const float4*)spatial,
                                               (float4*)out, (int4*)owner);
    // K2: resolve duplicate locations (last write wins)
    owner_kernel<<<(BATCH * NENT + 255) / 256, 256, 0, stream>>>(loc, owner);
    // K3: project + scatter winners
    proj_scatter_kernel<<<(BATCH * NENT * D_OUT + 255) / 256, 256, 0, stream>>>(
        emb, Wp, bp, loc, owner, out);
}

// Round 2
// 167.100 us; speedup vs baseline: 1.0292x; 1.0292x over previous
//
#include <hip/hip_runtime.h>

// Problem constants (from reference)
#define BATCH 16
#define NENT  512
#define D_IN  256
#define D_OUT 32
#define CSP   64
#define COUT  96        // 64 spatial + 32 scatter channels
#define HWDIM 256
#define HWSZ  65536     // 256*256
#define HW4   16384     // HWSZ/4
#define SP_B4  (CSP * HW4)   // 2^20  float4 per batch in spatial
#define OUT_B4 (COUT * HW4)  // 1,572,864 float4 per batch in out

// K_A: zero owner[] (int4) AND compute proj[b,n,e] into ws (independent work,
// fused to save a launch). Blocks 0..1023 zero; blocks 1024..2047 project.
__global__ void init_proj_kernel(const float* __restrict__ emb,
                                 const float* __restrict__ Wp,
                                 const float* __restrict__ bp,
                                 int4* __restrict__ owner4,
                                 float* __restrict__ projbuf) {
    int tid = blockIdx.x * blockDim.x + threadIdx.x;
    const int NZ4 = BATCH * HWSZ / 4;              // 262,144 int4 zeros
    if (tid < NZ4) {
        owner4[tid] = make_int4(0, 0, 0, 0);
        return;
    }
    int gid = tid - NZ4;                           // 0 .. 262,143
    int ent = gid >> 5;                            // entity 0..8191
    int e   = gid & 31;                            // feature 0..31
    float acc = bp[e];
    const float* er = emb + ent * D_IN;            // broadcast across 32 lanes
    #pragma unroll 8
    for (int d = 0; d < D_IN; ++d) {
        acc += er[d] * Wp[d * D_OUT + e];          // Wp coalesced across lanes
    }
    projbuf[gid] = acc;                            // coalesced
}

// K_B: last-write-wins resolution. owner[b, flat] = max(n+1).
__global__ void owner_kernel(const int* __restrict__ loc,
                             int* __restrict__ owner) {
    int gid = blockIdx.x * blockDim.x + threadIdx.x;   // 0 .. 8191
    if (gid >= BATCH * NENT) return;
    int h = loc[gid * 2 + 0];
    int w = loc[gid * 2 + 1];
    h = min(max(h, 0), HWDIM - 1);
    w = min(max(w, 0), HWDIM - 1);
    int b = gid >> 9;
    int n = gid & (NENT - 1);
    atomicMax(&owner[b * HWSZ + h * HWDIM + w], n + 1);
}

// K_C: pure float4 copy spatial -> out[:, :64]. All index math is shifts.
__global__ void copy_kernel(const float4* __restrict__ sp,
                            float4* __restrict__ out) {
    const int total = BATCH * SP_B4;               // 16,777,216 float4
    const int stride = gridDim.x * blockDim.x;
    for (int i = blockIdx.x * blockDim.x + threadIdx.x; i < total; i += stride) {
        int b   = i >> 20;                          // SP_B4 == 2^20
        int rem = i & (SP_B4 - 1);
        out[b * OUT_B4 + rem] = sp[i];
    }
}

// K_D: write out[:, 64:96] in full coalesced float4 streams; winner lanes
// gather their proj row (L2-resident, ~0.8% of lanes), others store zeros.
__global__ void scatter_fill_kernel(const int4* __restrict__ owner4,
                                    const float* __restrict__ projbuf,
                                    float4* __restrict__ out) {
    int tid = blockIdx.x * blockDim.x + threadIdx.x;   // 0 .. 262,143
    if (tid >= BATCH * HW4) return;
    int b   = tid >> 14;                            // HW4 == 2^14
    int hw4 = tid & (HW4 - 1);
    int4 ow = owner4[tid];                          // owner for 4 pixels
    const float* pb = projbuf + b * (NENT * D_OUT);
    float4* ob = out + b * OUT_B4 + CSP * HW4 + hw4;
    #pragma unroll 4
    for (int e = 0; e < D_OUT; ++e) {
        float4 v;
        v.x = ow.x ? pb[(ow.x - 1) * D_OUT + e] : 0.f;
        v.y = ow.y ? pb[(ow.y - 1) * D_OUT + e] : 0.f;
        v.z = ow.z ? pb[(ow.z - 1) * D_OUT + e] : 0.f;
        v.w = ow.w ? pb[(ow.w - 1) * D_OUT + e] : 0.f;
        ob[e * HW4] = v;                            // coalesced 16 B/lane
    }
}

extern "C" void kernel_launch(void* const* d_in, const int* in_sizes, int n_in,
                              void* d_out, int out_size, void* d_ws, size_t ws_size,
                              hipStream_t stream) {
    const float* spatial = (const float*)d_in[0];   // [16,64,256,256]
    const float* emb     = (const float*)d_in[1];   // [16,512,256]
    const float* Wp      = (const float*)d_in[2];   // [256,32]
    const float* bp      = (const float*)d_in[3];   // [32]
    const int*   loc     = (const int*)d_in[4];     // [16,512,2]
    float* out = (float*)d_out;                     // [16,96,256,256]

    int*   owner   = (int*)d_ws;                             // 4 MB
    float* projbuf = (float*)((char*)d_ws + BATCH * HWSZ * sizeof(int)); // 1 MB

    // A: zero owner + compute proj (independent, fused)
    init_proj_kernel<<<2048, 256, 0, stream>>>(emb, Wp, bp, (int4*)owner, projbuf);
    // B: resolve duplicate locations (last write wins)
    owner_kernel<<<32, 256, 0, stream>>>(loc, owner);
    // C: bulk spatial copy
    copy_kernel<<<2048, 256, 0, stream>>>((const float4*)spatial, (float4*)out);
    // D: scatter channels as pure coalesced store stream
    scatter_fill_kernel<<<1024, 256, 0, stream>>>((const int4*)owner, projbuf,
                                                  (float4*)out);
}

// Round 3
// 161.435 us; speedup vs baseline: 1.0653x; 1.0351x over previous
//
#include <hip/hip_runtime.h>

// Problem constants (from reference)
#define BATCH 16
#define NENT  512
#define D_IN  256
#define D_OUT 32
#define CSP   64
#define COUT  96        // 64 spatial + 32 scatter channels
#define HWDIM 256
#define HWSZ  65536     // 256*256
#define HW4   16384     // HWSZ/4
#define SP_B4  (CSP * HW4)   // float4 per batch in spatial (2^20)
#define OUT_B4 (COUT * HW4)  // float4 per batch in out

// K_A: zero owner[] (int4) AND compute proj[b,n,e] into ws.
// Exactly 2048 blocks x 256: first 262144 threads zero, rest project.
__global__ void init_proj_kernel(const float* __restrict__ emb,
                                 const float* __restrict__ Wp,
                                 const float* __restrict__ bp,
                                 int4* __restrict__ owner4,
                                 float* __restrict__ projbuf) {
    int tid = blockIdx.x * blockDim.x + threadIdx.x;
    const int NZ4 = BATCH * HWSZ / 4;              // 262,144 int4 zeros
    if (tid < NZ4) {
        owner4[tid] = make_int4(0, 0, 0, 0);
        return;
    }
    int gid = tid - NZ4;                           // 0 .. 262,143
    int ent = gid >> 5;                            // entity 0..8191
    int e   = gid & 31;                            // feature 0..31
    float acc = bp[e];
    const float* er = emb + ent * D_IN;            // broadcast within 32 lanes
    #pragma unroll 8
    for (int d = 0; d < D_IN; ++d) {
        acc += er[d] * Wp[d * D_OUT + e];          // Wp coalesced across lanes
    }
    projbuf[gid] = acc;                            // coalesced
}

// K_B: last-write-wins resolution. owner[b, flat] = max(n+1).
__global__ void owner_kernel(const int* __restrict__ loc,
                             int* __restrict__ owner) {
    int gid = blockIdx.x * blockDim.x + threadIdx.x;   // 0 .. 8191
    if (gid >= BATCH * NENT) return;
    int h = loc[gid * 2 + 0];
    int w = loc[gid * 2 + 1];
    h = min(max(h, 0), HWDIM - 1);
    w = min(max(w, 0), HWDIM - 1);
    int b = gid >> 9;
    int n = gid & (NENT - 1);
    atomicMax(&owner[b * HWSZ + h * HWDIM + w], n + 1);
}

// K_C: single pass over the whole output. Thread = (b, half, hw4 column).
// half 0: copy spatial channels 0..31  + fill scatter channels 0..15
// half 1: copy spatial channels 32..63 + fill scatter channels 16..31
__global__ void fused_out_kernel(const float4* __restrict__ sp,
                                 const int4* __restrict__ owner4,
                                 const float* __restrict__ projbuf,
                                 float4* __restrict__ out) {
    int tid  = blockIdx.x * blockDim.x + threadIdx.x;  // 0 .. 524,287
    int hw4  = tid & (HW4 - 1);
    int rest = tid >> 14;
    int half = rest & 1;
    int b    = rest >> 1;

    const float4* s = sp + (b * CSP + 32 * half) * HW4 + hw4;
    float4*       o = out + b * OUT_B4 + 32 * half * HW4 + hw4;

    // copy 32 spatial channels (coalesced 16 B/lane load+store)
    #pragma unroll 8
    for (int c = 0; c < 32; ++c) {
        o[c * HW4] = s[c * HW4];
    }

    // scatter-fill 16 channels
    int4 ow = owner4[b * HW4 + hw4];
    const float* pb = projbuf + b * (NENT * D_OUT) + 16 * half;
    float4* oz = out + b * OUT_B4 + (CSP + 16 * half) * HW4 + hw4;
    #pragma unroll 4
    for (int e = 0; e < 16; ++e) {
        float4 v;
        v.x = ow.x ? pb[(ow.x - 1) * D_OUT + e] : 0.f;
        v.y = ow.y ? pb[(ow.y - 1) * D_OUT + e] : 0.f;
        v.z = ow.z ? pb[(ow.z - 1) * D_OUT + e] : 0.f;
        v.w = ow.w ? pb[(ow.w - 1) * D_OUT + e] : 0.f;
        oz[e * HW4] = v;
    }
}

extern "C" void kernel_launch(void* const* d_in, const int* in_sizes, int n_in,
                              void* d_out, int out_size, void* d_ws, size_t ws_size,
                              hipStream_t stream) {
    const float* spatial = (const float*)d_in[0];   // [16,64,256,256]
    const float* emb     = (const float*)d_in[1];   // [16,512,256]
    const float* Wp      = (const float*)d_in[2];   // [256,32]
    const float* bp      = (const float*)d_in[3];   // [32]
    const int*   loc     = (const int*)d_in[4];     // [16,512,2]
    float* out = (float*)d_out;                     // [16,96,256,256]

    int*   owner   = (int*)d_ws;                             // 4 MB
    float* projbuf = (float*)((char*)d_ws + BATCH * HWSZ * sizeof(int)); // 1 MB

    // A: zero owner + compute proj (independent work, one launch)
    init_proj_kernel<<<2048, 256, 0, stream>>>(emb, Wp, bp, (int4*)owner, projbuf);
    // B: resolve duplicate locations (last write wins)
    owner_kernel<<<32, 256, 0, stream>>>(loc, owner);
    // C: single fused pass writing all 96 output channels
    fused_out_kernel<<<2048, 256, 0, stream>>>((const float4*)spatial,
                                               (const int4*)owner, projbuf,
                                               (float4*)out);
}

// Round 4
// 143.356 us; speedup vs baseline: 1.1997x; 1.1261x over previous
//
#include <hip/hip_runtime.h>

// Problem constants (from reference)
#define BATCH 16
#define NENT  512
#define D_IN  256
#define D_OUT 32
#define CSP   64
#define COUT  96        // 64 spatial + 32 scatter channels
#define HWDIM 256
#define HWSZ  65536     // 256*256
#define HW4   16384     // HWSZ/4  (2^14)
#define SP_B4  (CSP * HW4)   // 2^20 float4 per batch in spatial / out-spatial part
#define SC_B4  (D_OUT * HW4) // 2^19 float4 per batch in scatter part
#define OUT_B4 (COUT * HW4)  // 1,572,864 float4 per batch in out

// K_A: zero owner[] (int4) AND compute proj[b,n,e] into ws.
__global__ void init_proj_kernel(const float* __restrict__ emb,
                                 const float* __restrict__ Wp,
                                 const float* __restrict__ bp,
                                 int4* __restrict__ owner4,
                                 float* __restrict__ projbuf) {
    int tid = blockIdx.x * blockDim.x + threadIdx.x;
    const int NZ4 = BATCH * HWSZ / 4;              // 262,144 int4 zeros
    if (tid < NZ4) {
        owner4[tid] = make_int4(0, 0, 0, 0);
        return;
    }
    int gid = tid - NZ4;                           // 0 .. 262,143
    int ent = gid >> 5;                            // entity 0..8191
    int e   = gid & 31;                            // feature 0..31
    float acc = bp[e];
    const float* er = emb + ent * D_IN;            // broadcast within 32 lanes
    #pragma unroll 8
    for (int d = 0; d < D_IN; ++d) {
        acc += er[d] * Wp[d * D_OUT + e];          // Wp coalesced across lanes
    }
    projbuf[gid] = acc;                            // coalesced
}

// K_B: last-write-wins resolution. owner[b, flat] = max(n+1).
__global__ void owner_kernel(const int* __restrict__ loc,
                             int* __restrict__ owner) {
    int gid = blockIdx.x * blockDim.x + threadIdx.x;   // 0 .. 8191
    if (gid >= BATCH * NENT) return;
    int h = loc[gid * 2 + 0];
    int w = loc[gid * 2 + 1];
    h = min(max(h, 0), HWDIM - 1);
    w = min(max(w, 0), HWDIM - 1);
    int b = gid >> 9;
    int n = gid & (NENT - 1);
    atomicMax(&owner[b * HWSZ + h * HWDIM + w], n + 1);
}

// K_C: single linear pass over the output. gridDim = (2048, BATCH).
// 524,288 threads per batch; each does exactly:
//   iter 0: out[b][t]          = sp[b][t]            (linear copy)
//   iter 1: out[b][t + 2^19]   = sp[b][t + 2^19]     (linear copy)
//   iter 2: out[b][2^20 + t]   = scatter fill        (linear store)
// No runtime branches; all index math is shifts/masks.
__global__ void fused_out_kernel(const float4* __restrict__ sp,
                                 const int4* __restrict__ owner4,
                                 const float* __restrict__ projbuf,
                                 float4* __restrict__ out) {
    const int PER = 2048 * 256;                        // threads per batch slice
    int b = blockIdx.y;
    int t = blockIdx.x * blockDim.x + threadIdx.x;     // 0 .. PER-1

    const float4* spb  = sp  + (size_t)b * SP_B4;
    float4*       outb = out + (size_t)b * OUT_B4;

    // two pure linear copy quanta (covers 2^20 float4 = 64 channels)
    outb[t]        = spb[t];
    outb[t + PER]  = spb[t + PER];

    // scatter quantum: t covers 2^19 float4 = 32 channels x HW4
    int e   = t >> 14;                                 // channel 0..31
    int hw4 = t & (HW4 - 1);
    int4 ow = owner4[b * HW4 + hw4];                   // L2-resident (4 MB)
    const float* pb = projbuf + b * (NENT * D_OUT) + e;
    float4 v;
    v.x = ow.x ? pb[(ow.x - 1) * D_OUT] : 0.f;
    v.y = ow.y ? pb[(ow.y - 1) * D_OUT] : 0.f;
    v.z = ow.z ? pb[(ow.z - 1) * D_OUT] : 0.f;
    v.w = ow.w ? pb[(ow.w - 1) * D_OUT] : 0.f;
    outb[SP_B4 + t] = v;
}

extern "C" void kernel_launch(void* const* d_in, const int* in_sizes, int n_in,
                              void* d_out, int out_size, void* d_ws, size_t ws_size,
                              hipStream_t stream) {
    const float* spatial = (const float*)d_in[0];   // [16,64,256,256]
    const float* emb     = (const float*)d_in[1];   // [16,512,256]
    const float* Wp      = (const float*)d_in[2];   // [256,32]
    const float* bp      = (const float*)d_in[3];   // [32]
    const int*   loc     = (const int*)d_in[4];     // [16,512,2]
    float* out = (float*)d_out;                     // [16,96,256,256]

    int*   owner   = (int*)d_ws;                             // 4 MB
    float* projbuf = (float*)((char*)d_ws + BATCH * HWSZ * sizeof(int)); // 1 MB

    // A: zero owner + compute proj (independent work, one launch)
    init_proj_kernel<<<2048, 256, 0, stream>>>(emb, Wp, bp, (int4*)owner, projbuf);
    // B: resolve duplicate locations (last write wins)
    owner_kernel<<<32, 256, 0, stream>>>(loc, owner);
    // C: single linear pass writing all 96 output channels
    dim3 grid(2048, BATCH);
    fused_out_kernel<<<grid, 256, 0, stream>>>((const float4*)spatial,
                                               (const int4*)owner, projbuf,
                                               (float4*)out);
}